// Round 11
// baseline (305.925 us; speedup 1.0000x reference)
//
#include <hip/hip_runtime.h>
#include <math.h>
#include <stdint.h>

// Problem constants (fixed by setup_inputs)
#define E_EDGES 16384
#define H_DIM   256
#define S_SEEDS 32
#define NHEADS  8
#define HDIM    32
#define BGRAPHS 16
#define EPG     1024
#define NCHUNK  256       // 64-edge chunks
#define CPG     16        // chunks per graph
#define RSQRT_HD 0.17677669529663687f

typedef __attribute__((ext_vector_type(8))) short bf16x8;   // 8 bf16 (4 VGPRs)
typedef __attribute__((ext_vector_type(4))) float f32x4;

__device__ inline unsigned short f2bf(float x) {            // round-to-nearest-even
    unsigned u = __float_as_uint(x);
    u += 0x7fff + ((u >> 16) & 1);
    return (unsigned short)(u >> 16);
}
__device__ inline float bf2f(unsigned int h) {
    return __uint_as_float((h & 0xffffu) << 16);
}
__device__ inline unsigned pack2(float a, float b) {
    return (unsigned)f2bf(a) | ((unsigned)f2bf(b) << 16);
}

// ---------------- K1: WcT[n][k] bf16, n<256: Wv col, n>=256: folded q@Wk score col
// Block 0 also zero-inits the grid-barrier counters used by k_fused.
__global__ __launch_bounds__(256) void k_wc(const float* __restrict__ Wv,
                                            const float* __restrict__ Wk,
                                            const float* __restrict__ Wq,
                                            const float* __restrict__ seed,
                                            unsigned short* __restrict__ WcT,
                                            unsigned int* __restrict__ counters) {
    int j = blockIdx.x;          // 0..511 output row (n), block-uniform
    int i = threadIdx.x;         // 0..255 (k index)
    if (j == 0 && i < 2) counters[i] = 0u;
    float val;
    if (j < H_DIM) {
        val = Wv[i * H_DIM + j];
    } else {
        int c = j - H_DIM;
        int h = c >> 5, s = c & 31;
        __shared__ float qp[8][33];
        __shared__ float qrow[HDIM];
        int d = i & 31, g = i >> 5;
        const float* wq = &Wq[(g * 32) * H_DIM + h * HDIM + d];
        const float* sd = &seed[s * H_DIM + g * 32];
        float p = 0.f;
        #pragma unroll
        for (int ii = 0; ii < 32; ++ii)
            p = fmaf(sd[ii], wq[(size_t)ii * H_DIM], p);
        qp[g][d] = p;
        __syncthreads();
        if (i < HDIM) {
            float qv = 0.f;
            #pragma unroll
            for (int g2 = 0; g2 < 8; ++g2) qv += qp[g2][i];
            qrow[i] = qv;
        }
        __syncthreads();
        const float* wk = &Wk[i * H_DIM + h * HDIM];
        float acc = 0.f;
        #pragma unroll
        for (int dd = 0; dd < HDIM; dd += 4) {
            float4 w = *(const float4*)&wk[dd];
            float4 qq = *(const float4*)&qrow[dd];
            acc = fmaf(w.x, qq.x, acc); acc = fmaf(w.y, qq.y, acc);
            acc = fmaf(w.z, qq.z, acc); acc = fmaf(w.w, qq.w, acc);
        }
        val = acc * RSQRT_HD;
    }
    WcT[j * H_DIM + i] = f2bf(val);
}

// ---------------- shared-memory phase structs ----------------
struct SMattn {
    unsigned short As[64][264];          // 33792 B (528B row stride)
    unsigned short Vt[256][72];          // 36864 B  V transposed [d][e]
    unsigned short Pt[256][72];          // 36864 B  P transposed [scorecol][e]
};                                       // = 107520 B -> 1 block/CU (binding), 8 waves
struct SMtail {
    float mjv[2][CPG][8], sgv[2][CPG][8], sscale[2][CPG][8];
    float arow[2][H_DIM];
    float ynorm[2][H_DIM];
    float red[2][4];
};
struct SMm2 { float red[2][H_DIM]; float hrow[H_DIM]; };

// ---------------- software grid barrier ----------------
// SAFE because: LDS 107.5 KB forces exactly 1 block/CU, grid = 256 = CU count
// -> all blocks co-resident, every block reaches the barrier.
// Release: per-thread fence (L2 writeback) + syncthreads; thread0 ACQ_REL add;
// spin with ACQUIRE loads (invalidates stale/poisoned lines); re-sync + fence.
__device__ inline void grid_sync(unsigned int* cnt) {
    __threadfence();
    __syncthreads();
    if (threadIdx.x == 0) {
        __hip_atomic_fetch_add(cnt, 1u, __ATOMIC_ACQ_REL, __HIP_MEMORY_SCOPE_AGENT);
        while (__hip_atomic_load(cnt, __ATOMIC_ACQUIRE, __HIP_MEMORY_SCOPE_AGENT) < 256u) {}
    }
    __syncthreads();
    __threadfence();
}

// ---------------- K2: fused attn + tail + mlp2, 256 blocks x 512 threads ----------------
__global__ __launch_bounds__(512) void k_fused(
        const float* __restrict__ A,    const unsigned short* __restrict__ WcT,
        const float* __restrict__ seed, const float* __restrict__ Wo,
        const float* __restrict__ bo,   const float* __restrict__ ln_g,
        const float* __restrict__ ln_b, const float* __restrict__ W1,
        const float* __restrict__ b1,   const float* __restrict__ W2,
        const float* __restrict__ b2,   float* __restrict__ outc,
        float* __restrict__ mg,         float* __restrict__ sg,
        float* __restrict__ part,       unsigned int* __restrict__ counters,
        float* __restrict__ out) {
    __shared__ union { SMattn attn; SMtail tail; SMm2 m2; } smu;
    int tid = threadIdx.x;

    // ===== Phase 1: attention per 64-edge chunk (R10 k_attn body, verbatim) =====
    {
        SMattn& sm = smu.attn;
        int chunk = blockIdx.x;
        int e0 = chunk * 64;
        int w = tid >> 6, lane = tid & 63;
        int lr = lane & 15, kg = lane >> 4;

        {   // A prologue: 64x256 fp32 -> bf16 LDS, all 512 threads
            int r = tid >> 3, cg8 = tid & 7;
            const float* ap = &A[(size_t)(e0 + r) * H_DIM + cg8 * 32];
            #pragma unroll
            for (int i = 0; i < 4; ++i) {
                float4 x = *(const float4*)&ap[i * 8];
                float4 y = *(const float4*)&ap[i * 8 + 4];
                uint4 o;
                o.x = pack2(x.x, x.y); o.y = pack2(x.z, x.w);
                o.z = pack2(y.x, y.y); o.w = pack2(y.z, y.w);
                *(uint4*)&sm.As[r][cg8 * 32 + i * 8] = o;
            }
        }
        __syncthreads();                     // As ready

        const unsigned short* brow = &WcT[(size_t)(w * 64 + lr) * H_DIM + kg * 8];
        uint4 bfr[2][4];
        #pragma unroll
        for (int ni = 0; ni < 4; ++ni) {
            bfr[0][ni] = *(const uint4*)(brow + (size_t)ni * 16 * H_DIM);
            bfr[1][ni] = *(const uint4*)(brow + (size_t)ni * 16 * H_DIM + 32);
        }
        f32x4 acc[4][4] = {};
        #pragma unroll
        for (int k = 0; k < 8; ++k) {
            bf16x8 af[4], bv[4];
            #pragma unroll
            for (int mi = 0; mi < 4; ++mi)
                af[mi] = *(const bf16x8*)&sm.As[mi * 16 + lr][k * 32 + kg * 8];
            #pragma unroll
            for (int ni = 0; ni < 4; ++ni)
                bv[ni] = *(const bf16x8*)&bfr[k & 1][ni];
            if (k < 6) {
                #pragma unroll
                for (int ni = 0; ni < 4; ++ni)
                    bfr[k & 1][ni] = *(const uint4*)(brow + (size_t)ni * 16 * H_DIM + (k + 2) * 32);
            }
            #pragma unroll
            for (int mi = 0; mi < 4; ++mi)
                #pragma unroll
                for (int ni = 0; ni < 4; ++ni)
                    acc[mi][ni] = __builtin_amdgcn_mfma_f32_16x16x32_bf16(
                        af[mi], bv[ni], acc[mi][ni], 0, 0, 0);
        }

        if (w < 4) {
            #pragma unroll
            for (int mi = 0; mi < 4; ++mi)
                #pragma unroll
                for (int ni = 0; ni < 4; ++ni)
                    #pragma unroll
                    for (int r = 0; r < 4; ++r)
                        sm.Vt[w * 64 + ni * 16 + lr][mi * 16 + kg * 4 + r] =
                            f2bf(acc[mi][ni][r]);
        } else {
            int wn = (w - 4) * 64;
            #pragma unroll
            for (int ni = 0; ni < 4; ++ni) {
                float m = -1e30f;
                #pragma unroll
                for (int mi = 0; mi < 4; ++mi)
                    #pragma unroll
                    for (int r = 0; r < 4; ++r) m = fmaxf(m, acc[mi][ni][r]);
                m = fmaxf(m, __shfl_xor(m, 16, 64));
                m = fmaxf(m, __shfl_xor(m, 32, 64));
                float sv = 0.f;
                #pragma unroll
                for (int mi = 0; mi < 4; ++mi)
                    #pragma unroll
                    for (int r = 0; r < 4; ++r) {
                        float e_ = __expf(acc[mi][ni][r] - m);
                        unsigned short eb = f2bf(e_);
                        sm.Pt[wn + ni * 16 + lr][mi * 16 + kg * 4 + r] = eb;
                        sv += bf2f(eb);
                    }
                sv += __shfl_xor(sv, 16, 64);
                sv += __shfl_xor(sv, 32, 64);
                if (kg == 0) {
                    mg[(size_t)chunk * H_DIM + wn + ni * 16 + lr] = m;
                    sg[(size_t)chunk * H_DIM + wn + ni * 16 + lr] = sv;
                }
            }
        }
        __syncthreads();                     // Vt + Pt ready

        f32x4 acc2[2][2] = {};
        #pragma unroll
        for (int ms = 0; ms < 2; ++ms)
            #pragma unroll
            for (int nd = 0; nd < 2; ++nd)
                #pragma unroll
                for (int kk = 0; kk < 2; ++kk) {
                    bf16x8 pa = *(const bf16x8*)&sm.Pt[w * 32 + ms * 16 + lr][kk * 32 + kg * 8];
                    bf16x8 vb = *(const bf16x8*)&sm.Vt[w * 32 + nd * 16 + lr][kk * 32 + kg * 8];
                    acc2[ms][nd] = __builtin_amdgcn_mfma_f32_16x16x32_bf16(
                        pa, vb, acc2[ms][nd], 0, 0, 0);
                }
        #pragma unroll
        for (int ms = 0; ms < 2; ++ms)
            #pragma unroll
            for (int nd = 0; nd < 2; ++nd)
                #pragma unroll
                for (int r = 0; r < 4; ++r) {
                    int s_ = ms * 16 + kg * 4 + r;
                    int c_ = w * 32 + nd * 16 + lr;
                    outc[((size_t)chunk * 32 + s_) * H_DIM + c_] = acc2[ms][nd][r];
                }
    }
    grid_sync(&counters[0]);

    // ===== Phase 2: tail — combine + Wo proj + LN + W1 partial =====
    // 2 (b,s) rows per block via 256-thread halves; math identical to R10.
    {
        SMtail& t = smu.tail;
        int half = tid >> 8, tl = tid & 255;
        int bs = blockIdx.x * 2 + half;       // 0..511
        int b = bs >> 5, s = bs & 31;
        // Phase A: stage chunk partials, combine with 8 threads per half
        if (tl < 128) {
            int j = tl >> 3, h = tl & 7;
            int sc = h * 32 + s;
            t.mjv[half][j][h] = mg[(size_t)(b * CPG + j) * H_DIM + sc];
            t.sgv[half][j][h] = sg[(size_t)(b * CPG + j) * H_DIM + sc];
        }
        __syncthreads();
        if (tl < 8) {
            int h = tl;
            float M = -1e30f;
            #pragma unroll
            for (int j = 0; j < CPG; ++j) M = fmaxf(M, t.mjv[half][j][h]);
            float Den = 0.f;
            #pragma unroll
            for (int j = 0; j < CPG; ++j)
                Den += t.sgv[half][j][h] * __expf(t.mjv[half][j][h] - M);
            float inv = 1.f / Den;
            #pragma unroll
            for (int j = 0; j < CPG; ++j)
                t.sscale[half][j][h] = __expf(t.mjv[half][j][h] - M) * inv;
        }
        __syncthreads();
        // Phase B: att assembly (16 loads in flight)
        {
            int h = tl >> 5;
            float a = 0.f;
            #pragma unroll
            for (int j = 0; j < CPG; ++j)
                a = fmaf(outc[((size_t)(b * CPG + j) * 32 + s) * H_DIM + tl],
                         t.sscale[half][j][h], a);
            t.arow[half][tl] = a;
        }
        __syncthreads();
        // Phase C: y = seed + bo + arow @ Wo[:,c]  (32-wide load batches)
        float y = bo[tl] + seed[s * H_DIM + tl];
        #pragma unroll 1
        for (int i = 0; i < H_DIM; i += 32) {
            float wv[32];
            #pragma unroll
            for (int k = 0; k < 32; ++k)
                wv[k] = Wo[(size_t)(i + k) * H_DIM + tl];
            #pragma unroll
            for (int k = 0; k < 32; ++k)
                y = fmaf(t.arow[half][i + k], wv[k], y);
        }
        // Phase D: LN (per-half 4-wave reduce, same op order as R10)
        int wid4 = (tid >> 6) & 3;
        float v = y;
        #pragma unroll
        for (int o = 32; o > 0; o >>= 1) v += __shfl_xor(v, o, 64);
        if ((tid & 63) == 0) t.red[half][wid4] = v;
        __syncthreads();
        float mu = (t.red[half][0] + t.red[half][1] + t.red[half][2] + t.red[half][3])
                   * (1.f / 256.f);
        __syncthreads();
        float d = y - mu;
        v = d * d;
        #pragma unroll
        for (int o = 32; o > 0; o >>= 1) v += __shfl_xor(v, o, 64);
        if ((tid & 63) == 0) t.red[half][wid4] = v;
        __syncthreads();
        float var = (t.red[half][0] + t.red[half][1] + t.red[half][2] + t.red[half][3])
                    * (1.f / 256.f);
        t.ynorm[half][tl] = d * rsqrtf(var + 1e-5f) * ln_g[tl] + ln_b[tl];
        __syncthreads();
        // Phase E: W1 partial (32-wide load batches)
        {
            const float* w1p = &W1[(size_t)(s * H_DIM) * H_DIM + tl];
            float acc = 0.f;
            #pragma unroll 1
            for (int i = 0; i < H_DIM; i += 32) {
                float wv[32];
                #pragma unroll
                for (int k = 0; k < 32; ++k)
                    wv[k] = w1p[(size_t)(i + k) * H_DIM];
                #pragma unroll
                for (int k = 0; k < 32; ++k)
                    acc = fmaf(t.ynorm[half][i + k], wv[k], acc);
            }
            part[((size_t)s * BGRAPHS + b) * H_DIM + tl] = acc;
        }
    }
    grid_sync(&counters[1]);

    // ===== Phase 3: mlp2 on blocks 0..15 (2 reduce groups of 16 s-chunks) =====
    if (blockIdx.x < 16) {
        SMm2& m = smu.m2;
        int b = blockIdx.x;
        int c = tid & 255, g = tid >> 8;
        float sacc = 0.f;
        #pragma unroll
        for (int sc2 = g * 16; sc2 < g * 16 + 16; ++sc2)
            sacc += part[((size_t)sc2 * BGRAPHS + b) * H_DIM + c];
        m.red[g][c] = sacc;
        __syncthreads();
        if (g == 0) {
            float s = m.red[0][c] + m.red[1][c] + b1[c];
            m.hrow[c] = s / (1.f + __expf(-s));
        }
        __syncthreads();
        float wacc = 0.f;
        #pragma unroll 1
        for (int j0 = g * 128; j0 < g * 128 + 128; j0 += 32) {
            float wv[32];
            #pragma unroll
            for (int k = 0; k < 32; ++k)
                wv[k] = W2[(size_t)(j0 + k) * H_DIM + c];
            #pragma unroll
            for (int k = 0; k < 32; ++k)
                wacc = fmaf(m.hrow[j0 + k], wv[k], wacc);
        }
        m.red[g][c] = wacc;
        __syncthreads();
        if (g == 0)
            out[(size_t)b * H_DIM + c] = m.red[0][c] + m.red[1][c] + b2[c];
    }
}

extern "C" void kernel_launch(void* const* d_in, const int* in_sizes, int n_in,
                              void* d_out, int out_size, void* d_ws, size_t ws_size,
                              hipStream_t stream) {
    const float* edge_features = (const float*)d_in[0];
    const float* seed = (const float*)d_in[3];
    const float* Wq   = (const float*)d_in[4];
    const float* Wk   = (const float*)d_in[5];
    const float* Wv   = (const float*)d_in[6];
    const float* Wo   = (const float*)d_in[7];
    const float* bo   = (const float*)d_in[8];
    const float* ln_g = (const float*)d_in[9];
    const float* ln_b = (const float*)d_in[10];
    const float* W1   = (const float*)d_in[11];
    const float* b1   = (const float*)d_in[12];
    const float* W2   = (const float*)d_in[13];
    const float* b2   = (const float*)d_in[14];
    float* out = (float*)d_out;

    // Workspace layout (floats)
    float* ws = (float*)d_ws;
    unsigned short* WcT = (unsigned short*)ws;                    // 512*256 u16 (65536 f)
    float* outc = ws + 65536;                                     // 256*32*256 = 2097152
    float* mg   = outc + 2097152;                                 // 65536
    float* sg   = mg + 65536;                                     // 65536
    float* part = sg + 65536;                                     // 32*16*256 = 131072
    unsigned int* counters = (unsigned int*)(part + 131072);      // 2 u32
    // total ~= 2.4M floats ~= 9.7 MB

    k_wc    <<<512, 256, 0, stream>>>(Wv, Wk, Wq, seed, WcT, counters);
    k_fused <<<NCHUNK, 512, 0, stream>>>(edge_features, WcT, seed, Wo, bo, ln_g,
                                         ln_b, W1, b1, W2, b2, outc, mg, sg,
                                         part, counters, out);
}

// Round 12
// 134.412 us; speedup vs baseline: 2.2760x; 2.2760x over previous
//
#include <hip/hip_runtime.h>
#include <math.h>
#include <stdint.h>

// Problem constants (fixed by setup_inputs)
#define E_EDGES 16384
#define H_DIM   256
#define S_SEEDS 32
#define NHEADS  8
#define HDIM    32
#define BGRAPHS 16
#define EPG     1024
#define NCHUNK  256       // 64-edge chunks
#define CPG     16        // chunks per graph
#define RSQRT_HD 0.17677669529663687f

typedef __attribute__((ext_vector_type(8))) short bf16x8;   // 8 bf16 (4 VGPRs)
typedef __attribute__((ext_vector_type(4))) float f32x4;

__device__ inline unsigned short f2bf(float x) {            // round-to-nearest-even
    unsigned u = __float_as_uint(x);
    u += 0x7fff + ((u >> 16) & 1);
    return (unsigned short)(u >> 16);
}
__device__ inline float bf2f(unsigned int h) {
    return __uint_as_float((h & 0xffffu) << 16);
}
__device__ inline unsigned pack2(float a, float b) {
    return (unsigned)f2bf(a) | ((unsigned)f2bf(b) << 16);
}

// ---------------- K1: WcT[n][k] bf16, n<256: Wv col, n>=256: folded q@Wk score col
__global__ __launch_bounds__(256) void k_wc(const float* __restrict__ Wv,
                                            const float* __restrict__ Wk,
                                            const float* __restrict__ Wq,
                                            const float* __restrict__ seed,
                                            unsigned short* __restrict__ WcT) {
    int j = blockIdx.x;          // 0..511 output row (n), block-uniform
    int i = threadIdx.x;         // 0..255 (k index)
    float val;
    if (j < H_DIM) {
        val = Wv[i * H_DIM + j];
    } else {
        int c = j - H_DIM;
        int h = c >> 5, s = c & 31;
        __shared__ float qp[8][33];
        __shared__ float qrow[HDIM];
        int d = i & 31, g = i >> 5;
        const float* wq = &Wq[(g * 32) * H_DIM + h * HDIM + d];
        const float* sd = &seed[s * H_DIM + g * 32];
        float p = 0.f;
        #pragma unroll
        for (int ii = 0; ii < 32; ++ii)
            p = fmaf(sd[ii], wq[(size_t)ii * H_DIM], p);
        qp[g][d] = p;
        __syncthreads();
        if (i < HDIM) {
            float qv = 0.f;
            #pragma unroll
            for (int g2 = 0; g2 < 8; ++g2) qv += qp[g2][i];
            qrow[i] = qv;
        }
        __syncthreads();
        const float* wk = &Wk[i * H_DIM + h * HDIM];
        float acc = 0.f;
        #pragma unroll
        for (int dd = 0; dd < HDIM; dd += 4) {
            float4 w = *(const float4*)&wk[dd];
            float4 qq = *(const float4*)&qrow[dd];
            acc = fmaf(w.x, qq.x, acc); acc = fmaf(w.y, qq.y, acc);
            acc = fmaf(w.z, qq.z, acc); acc = fmaf(w.w, qq.w, acc);
        }
        val = acc * RSQRT_HD;
    }
    WcT[j * H_DIM + i] = f2bf(val);
}

// ---------------- K2: fused attention per 64-edge chunk, 512 threads ----------------
// (2-barrier free-running schedule)
struct SMattn {
    unsigned short As[64][264];          // 33792 B (528B row stride)
    unsigned short Vt[256][72];          // 36864 B  V transposed [d][e]
    unsigned short Pt[256][72];          // 36864 B  P transposed [scorecol][e]
};                                       // = 107520 B -> 1 block/CU, 8 waves

__global__ __launch_bounds__(512) void k_attn(const float* __restrict__ A,
                                              const unsigned short* __restrict__ WcT,
                                              float* __restrict__ outc,
                                              float* __restrict__ mg,
                                              float* __restrict__ sg) {
    __shared__ SMattn sm;
    int tid = threadIdx.x;
    int chunk = blockIdx.x;
    int e0 = chunk * 64;
    int w = tid >> 6, lane = tid & 63;
    int lr = lane & 15, kg = lane >> 4;

    {   // A prologue: 64x256 fp32 -> bf16 LDS, all 512 threads
        int r = tid >> 3, cg8 = tid & 7;
        const float* ap = &A[(size_t)(e0 + r) * H_DIM + cg8 * 32];
        #pragma unroll
        for (int i = 0; i < 4; ++i) {
            float4 x = *(const float4*)&ap[i * 8];
            float4 y = *(const float4*)&ap[i * 8 + 4];
            uint4 o;
            o.x = pack2(x.x, x.y); o.y = pack2(x.z, x.w);
            o.z = pack2(y.x, y.y); o.w = pack2(y.z, y.w);
            *(uint4*)&sm.As[r][cg8 * 32 + i * 8] = o;
        }
    }
    __syncthreads();                     // barrier 1: As ready

    const unsigned short* brow = &WcT[(size_t)(w * 64 + lr) * H_DIM + kg * 8];
    uint4 bfr[2][4];
    #pragma unroll
    for (int ni = 0; ni < 4; ++ni) {
        bfr[0][ni] = *(const uint4*)(brow + (size_t)ni * 16 * H_DIM);
        bfr[1][ni] = *(const uint4*)(brow + (size_t)ni * 16 * H_DIM + 32);
    }
    f32x4 acc[4][4] = {};
    #pragma unroll
    for (int k = 0; k < 8; ++k) {
        bf16x8 af[4], bv[4];
        #pragma unroll
        for (int mi = 0; mi < 4; ++mi)
            af[mi] = *(const bf16x8*)&sm.As[mi * 16 + lr][k * 32 + kg * 8];
        #pragma unroll
        for (int ni = 0; ni < 4; ++ni)
            bv[ni] = *(const bf16x8*)&bfr[k & 1][ni];
        if (k < 6) {
            #pragma unroll
            for (int ni = 0; ni < 4; ++ni)
                bfr[k & 1][ni] = *(const uint4*)(brow + (size_t)ni * 16 * H_DIM + (k + 2) * 32);
        }
        #pragma unroll
        for (int mi = 0; mi < 4; ++mi)
            #pragma unroll
            for (int ni = 0; ni < 4; ++ni)
                acc[mi][ni] = __builtin_amdgcn_mfma_f32_16x16x32_bf16(
                    af[mi], bv[ni], acc[mi][ni], 0, 0, 0);
    }

    if (w < 4) {
        #pragma unroll
        for (int mi = 0; mi < 4; ++mi)
            #pragma unroll
            for (int ni = 0; ni < 4; ++ni)
                #pragma unroll
                for (int r = 0; r < 4; ++r)
                    sm.Vt[w * 64 + ni * 16 + lr][mi * 16 + kg * 4 + r] =
                        f2bf(acc[mi][ni][r]);
    } else {
        int wn = (w - 4) * 64;
        #pragma unroll
        for (int ni = 0; ni < 4; ++ni) {
            float m = -1e30f;
            #pragma unroll
            for (int mi = 0; mi < 4; ++mi)
                #pragma unroll
                for (int r = 0; r < 4; ++r) m = fmaxf(m, acc[mi][ni][r]);
            m = fmaxf(m, __shfl_xor(m, 16, 64));
            m = fmaxf(m, __shfl_xor(m, 32, 64));
            float sv = 0.f;
            #pragma unroll
            for (int mi = 0; mi < 4; ++mi)
                #pragma unroll
                for (int r = 0; r < 4; ++r) {
                    float e_ = __expf(acc[mi][ni][r] - m);
                    unsigned short eb = f2bf(e_);
                    sm.Pt[wn + ni * 16 + lr][mi * 16 + kg * 4 + r] = eb;
                    sv += bf2f(eb);
                }
            sv += __shfl_xor(sv, 16, 64);
            sv += __shfl_xor(sv, 32, 64);
            if (kg == 0) {
                mg[(size_t)chunk * H_DIM + wn + ni * 16 + lr] = m;
                sg[(size_t)chunk * H_DIM + wn + ni * 16 + lr] = sv;
            }
        }
    }
    __syncthreads();                     // barrier 2: Vt + Pt ready

    f32x4 acc2[2][2] = {};
    #pragma unroll
    for (int ms = 0; ms < 2; ++ms)
        #pragma unroll
        for (int nd = 0; nd < 2; ++nd)
            #pragma unroll
            for (int kk = 0; kk < 2; ++kk) {
                bf16x8 pa = *(const bf16x8*)&sm.Pt[w * 32 + ms * 16 + lr][kk * 32 + kg * 8];
                bf16x8 vb = *(const bf16x8*)&sm.Vt[w * 32 + nd * 16 + lr][kk * 32 + kg * 8];
                acc2[ms][nd] = __builtin_amdgcn_mfma_f32_16x16x32_bf16(
                    pa, vb, acc2[ms][nd], 0, 0, 0);
            }
    #pragma unroll
    for (int ms = 0; ms < 2; ++ms)
        #pragma unroll
        for (int nd = 0; nd < 2; ++nd)
            #pragma unroll
            for (int r = 0; r < 4; ++r) {
                int s_ = ms * 16 + kg * 4 + r;
                int c_ = w * 32 + nd * 16 + lr;
                outc[((size_t)chunk * 32 + s_) * H_DIM + c_] = acc2[ms][nd][r];
            }
}

// ---------------- block reduction helper (256 threads = 4 waves) ----------------
__device__ inline float block_sum256(float v, float* red4) {
    for (int o = 32; o > 0; o >>= 1) v += __shfl_xor(v, o, 64);
    int wid = threadIdx.x >> 6;
    if ((threadIdx.x & 63) == 0) red4[wid] = v;
    __syncthreads();
    float r = red4[0] + red4[1] + red4[2] + red4[3];
    __syncthreads();
    return r;
}

// ---------------- K3: tail = combine + Wo proj + LN + W1 partial ----------------
// 512 blocks x 1 (b,s) row. Phases C/E use 32-wide explicit load batching
// (fixes the VGPR=24 / 4-loads-in-flight latency exposure measured in R9).
__global__ __launch_bounds__(256) void k_tail(const float* __restrict__ outc,
                                              const float* __restrict__ mg,
                                              const float* __restrict__ sg,
                                              const float* __restrict__ seed,
                                              const float* __restrict__ Wo,
                                              const float* __restrict__ bo,
                                              const float* __restrict__ ln_g,
                                              const float* __restrict__ ln_b,
                                              const float* __restrict__ W1,
                                              float* __restrict__ part) {
    int bs = blockIdx.x;                  // 0..511
    int b = bs >> 5, s = bs & 31;
    int c = threadIdx.x;
    __shared__ float mjv[CPG][8], sgv[CPG][8], sscale[CPG][8];
    __shared__ float arow[H_DIM];
    __shared__ float ynorm[H_DIM];
    __shared__ float red4[4];
    // Phase A: stage chunk partials (128 parallel loads), combine with 8 threads
    if (c < 128) {
        int j = c >> 3, h = c & 7;
        int sc = h * 32 + s;
        mjv[j][h] = mg[(size_t)(b * CPG + j) * H_DIM + sc];
        sgv[j][h] = sg[(size_t)(b * CPG + j) * H_DIM + sc];
    }
    __syncthreads();
    if (c < 8) {
        int h = c;
        float M = -1e30f;
        #pragma unroll
        for (int j = 0; j < CPG; ++j) M = fmaxf(M, mjv[j][h]);
        float Den = 0.f;
        #pragma unroll
        for (int j = 0; j < CPG; ++j) Den += sgv[j][h] * __expf(mjv[j][h] - M);
        float inv = 1.f / Den;
        #pragma unroll
        for (int j = 0; j < CPG; ++j) sscale[j][h] = __expf(mjv[j][h] - M) * inv;
    }
    __syncthreads();
    // Phase B: att assembly (16 loads in flight)
    {
        int h = c >> 5;
        float a = 0.f;
        #pragma unroll
        for (int j = 0; j < CPG; ++j)
            a = fmaf(outc[((size_t)(b * CPG + j) * 32 + s) * H_DIM + c],
                     sscale[j][h], a);
        arow[c] = a;
    }
    __syncthreads();
    // Phase C: y = seed + bo + arow @ Wo[:,c]  (32-wide load batches)
    float y = bo[c] + seed[s * H_DIM + c];
    #pragma unroll 1
    for (int i = 0; i < H_DIM; i += 32) {
        float wv[32];
        #pragma unroll
        for (int k = 0; k < 32; ++k)
            wv[k] = Wo[(size_t)(i + k) * H_DIM + c];
        #pragma unroll
        for (int k = 0; k < 32; ++k)
            y = fmaf(arow[i + k], wv[k], y);
    }
    // Phase D: LN -> ynorm in LDS
    float mu = block_sum256(y, red4) * (1.f / 256.f);
    float d = y - mu;
    float var = block_sum256(d * d, red4) * (1.f / 256.f);
    ynorm[c] = d * rsqrtf(var + 1e-5f) * ln_g[c] + ln_b[c];
    __syncthreads();
    // Phase E: W1 partial  part[s][b][c] = sum_i ynorm[i] * W1[s*256+i][c]
    {
        const float* w1p = &W1[(size_t)(s * H_DIM) * H_DIM + c];
        float acc = 0.f;
        #pragma unroll 1
        for (int i = 0; i < H_DIM; i += 32) {
            float wv[32];
            #pragma unroll
            for (int k = 0; k < 32; ++k)
                wv[k] = w1p[(size_t)(i + k) * H_DIM];
            #pragma unroll
            for (int k = 0; k < 32; ++k)
                acc = fmaf(ynorm[i + k], wv[k], acc);
        }
        part[((size_t)s * BGRAPHS + b) * H_DIM + c] = acc;
    }
}

// ---------------- K4: 4-way parallel reduce 32 partials + SiLU + @W2 + b2 ----
__global__ __launch_bounds__(1024) void k_mlp2(const float* __restrict__ part,
                                               const float* __restrict__ b1,
                                               const float* __restrict__ W2,
                                               const float* __restrict__ b2,
                                               float* __restrict__ out) {
    int b = blockIdx.x;
    int t = threadIdx.x;
    int c = t & 255, g = t >> 8;          // 4 reduce groups, 8 s-chunks each
    __shared__ float red[4][H_DIM];
    __shared__ float hrow[H_DIM];
    float sacc = 0.f;
    #pragma unroll
    for (int sc2 = g * 8; sc2 < g * 8 + 8; ++sc2)
        sacc += part[((size_t)sc2 * BGRAPHS + b) * H_DIM + c];
    red[g][c] = sacc;
    __syncthreads();
    if (g == 0) {
        float s = red[0][c] + red[1][c] + red[2][c] + red[3][c] + b1[c];
        hrow[c] = s / (1.f + __expf(-s));
    }
    __syncthreads();
    float wacc = 0.f;
    #pragma unroll 4
    for (int j = g * 64; j < g * 64 + 64; ++j)
        wacc = fmaf(hrow[j], W2[(size_t)j * H_DIM + c], wacc);
    red[g][c] = wacc;
    __syncthreads();
    if (g == 0)
        out[(size_t)b * H_DIM + c] = red[0][c] + red[1][c] + red[2][c] + red[3][c] + b2[c];
}

extern "C" void kernel_launch(void* const* d_in, const int* in_sizes, int n_in,
                              void* d_out, int out_size, void* d_ws, size_t ws_size,
                              hipStream_t stream) {
    const float* edge_features = (const float*)d_in[0];
    const float* seed = (const float*)d_in[3];
    const float* Wq   = (const float*)d_in[4];
    const float* Wk   = (const float*)d_in[5];
    const float* Wv   = (const float*)d_in[6];
    const float* Wo   = (const float*)d_in[7];
    const float* bo   = (const float*)d_in[8];
    const float* ln_g = (const float*)d_in[9];
    const float* ln_b = (const float*)d_in[10];
    const float* W1   = (const float*)d_in[11];
    const float* b1   = (const float*)d_in[12];
    const float* W2   = (const float*)d_in[13];
    const float* b2   = (const float*)d_in[14];
    float* out = (float*)d_out;

    // Workspace layout (floats)
    float* ws = (float*)d_ws;
    unsigned short* WcT = (unsigned short*)ws;                    // 512*256 u16 (65536 f)
    float* outc = ws + 65536;                                     // 256*32*256 = 2097152
    float* mg   = outc + 2097152;                                 // 65536
    float* sg   = mg + 65536;                                     // 65536
    float* part = sg + 65536;                                     // 32*16*256 = 131072
    // total ~= 2.4M floats ~= 9.7 MB

    k_wc   <<<512, 256, 0, stream>>>(Wv, Wk, Wq, seed, WcT);
    k_attn <<<NCHUNK, 512, 0, stream>>>(edge_features, WcT, outc, mg, sg);
    k_tail <<<512, 256, 0, stream>>>(outc, mg, sg, seed, Wo, bo, ln_g, ln_b, W1, part);
    k_mlp2 <<<BGRAPHS, 1024, 0, stream>>>(part, b1, W2, b2, out);
}